// Round 10
// baseline (391.807 us; speedup 1.0000x reference)
//
#include <hip/hip_runtime.h>
#include <hip/hip_bf16.h>

#define BATCH 128
#define TSEQ  256
#define NEMBD 384
#define NHEAD 6
#define HDIM  64
#define C3    1152
#define MROWS 32768      // BATCH*TSEQ
#define KGTOT 48         // NEMBD/8
#define NBH   768        // BATCH*NHEAD
#define BHSZ  16384      // TSEQ*HDIM (ushorts per bh per tensor)

#define NA_CH  (MROWS * KGTOT)   // 1572864 chunks (X)
#define NW1_CH (C3 * KGTOT)      // 55296 (Wqkv)
#define NW2_CH (NEMBD * KGTOT)   // 18432 (Wproj)

#define XBLOCKS 2048             // MROWS/16 row-blocks for X convert
#define WBLOCKS 288              // (NW1_CH+NW2_CH)/256 weight-convert blocks

typedef __attribute__((ext_vector_type(8))) short short8v;
typedef __attribute__((ext_vector_type(4))) float float4v;

// ---------- helpers ----------

__device__ __forceinline__ unsigned short f2bf(float f) {
  __hip_bfloat16 h = __float2bfloat16(f);   // RNE
  unsigned short u;
  __builtin_memcpy(&u, &h, 2);
  return u;
}

// ---------- fused converts ----------
__device__ __forceinline__ void convB_body(const float* __restrict__ W,
                                           unsigned short* __restrict__ out,
                                           int N, int idx) {
  const int nl  = idx & 127;
  const int kgg = (idx >> 7) % KGTOT;
  const int nb  = idx / (128 * KGTOT);
  const int n = nb * 128 + nl;
  short8v v;
#pragma unroll
  for (int j = 0; j < 8; ++j)
    v[j] = (short)f2bf(W[(size_t)(kgg * 8 + j) * N + n]);
  *reinterpret_cast<short8v*>(out + (size_t)idx * 8) = v;
}

__global__ __launch_bounds__(256)
void convert_all(const float* __restrict__ X, const float* __restrict__ W1,
                 const float* __restrict__ W2, unsigned short* __restrict__ Abf,
                 unsigned short* __restrict__ W1T, unsigned short* __restrict__ W2T) {
  const int tid = threadIdx.x;
  if (blockIdx.x < XBLOCKS) {
    __shared__ __attribute__((aligned(16))) unsigned short T[16][392];  // pad 384->392
    const int rb = blockIdx.x;
    const float* Xb = X + (size_t)rb * 16 * NEMBD;
#pragma unroll
    for (int i = 0; i < 6; ++i) {
      const int f4 = i * 256 + tid;          // float4 index 0..1535
      const float4 v = reinterpret_cast<const float4*>(Xb)[f4];
      const int r = f4 / 96;                 // 96 float4 per row
      const int c = (f4 % 96) * 4;
      ushort4 u;
      u.x = f2bf(v.x); u.y = f2bf(v.y); u.z = f2bf(v.z); u.w = f2bf(v.w);
      *reinterpret_cast<ushort4*>(&T[r][c]) = u;
    }
    __syncthreads();
#pragma unroll
    for (int i = 0; i < 3; ++i) {
      const int c2   = i * 256 + tid;        // chunk 0..767 = [kgg 48][ml16 16]
      const int kgg  = c2 >> 4;
      const int ml16 = c2 & 15;
      const short8v v = *reinterpret_cast<const short8v*>(&T[ml16][kgg * 8]);
      const int m  = rb * 16 + ml16;
      const int mb = m >> 7;
      const int ml = m & 127;
      *reinterpret_cast<short8v*>(Abf + ((size_t)(mb * KGTOT + kgg) * 128 + ml) * 8) = v;
    }
  } else {
    const int wi = (blockIdx.x - XBLOCKS) * 256 + tid;
    if (wi < NW1_CH) convB_body(W1, W1T, C3, wi);
    else             convB_body(W2, W2T, NEMBD, wi - NW1_CH);
  }
}

// ---------- GEMM core 256x128: BK=32, ping-pong gload_lds, 512 thr / 8 waves ----------
// R9 structure + __launch_bounds__(512, 6): forces VGPR <= ~85 so 3 blocks/CU
// fit (R9's 88 VGPR allowed only 2 -> occupancy fell 26%->17% and the
// amortization gain was eaten by lost cross-block latency hiding).
// LDS: A[4][256][8] 16KB + B[4][128][8] 8KB, ping-pong = 48KB; 3x48=144<=160.

#define GEMM_STAGE256(Ab2, Bb, kb, AL, BL)                                             \
  _Pragma("unroll") for (int p = 0; p < 2; ++p) {                                      \
    const int i   = p * 512 + tid;                                                     \
    const int kg  = i >> 8;                                                            \
    const int row = i & 255;                                                           \
    const size_t goff = ((size_t)((row >> 7) * KGTOT + (kb) * 4 + kg) * 128            \
                        + (row & 127)) * 8;                                            \
    __builtin_amdgcn_global_load_lds(                                                  \
        (const __attribute__((address_space(1))) unsigned int*)((Ab2) + goff),         \
        (__attribute__((address_space(3))) unsigned int*)((AL) + (kg * 256 + row) * 8),\
        16, 0, 0);                                                                     \
  }                                                                                    \
  {                                                                                    \
    const int kgB  = tid >> 7;                                                         \
    const int rowB = tid & 127;                                                        \
    const size_t goffB = ((size_t)((kb) * 4 + kgB) * 128 + rowB) * 8;                  \
    __builtin_amdgcn_global_load_lds(                                                  \
        (const __attribute__((address_space(1))) unsigned int*)((Bb) + goffB),         \
        (__attribute__((address_space(3))) unsigned int*)((BL) + (kgB * 128 + rowB) * 8),\
        16, 0, 0);                                                                     \
  }

#define GEMM_CORE256(Ab2, Bb)                                                          \
  __shared__ __attribute__((aligned(16))) unsigned short S[24576];                     \
  const int tid  = threadIdx.x;                                                        \
  const int wave = tid >> 6;                                                           \
  const int lane = tid & 63;                                                           \
  const int wm  = (wave & 3) * 64;                                                     \
  const int wn  = (wave >> 2) * 64;                                                    \
  const int l15 = lane & 15;                                                           \
  const int lq  = lane >> 4;                                                           \
  float4v acc[4][4];                                                                   \
  _Pragma("unroll") for (int i = 0; i < 4; ++i)                                        \
    _Pragma("unroll") for (int j = 0; j < 4; ++j)                                      \
      acc[i][j] = (float4v){0.f, 0.f, 0.f, 0.f};                                       \
  GEMM_STAGE256(Ab2, Bb, 0, S, S + 8192)                                               \
  for (int kb = 0; kb < KGTOT / 4; ++kb) {                                             \
    const int cur = (kb & 1) * 12288;                                                  \
    const int nxt = 12288 - cur;                                                       \
    __syncthreads();                                                                   \
    if (kb + 1 < KGTOT / 4) {                                                          \
      GEMM_STAGE256(Ab2, Bb, kb + 1, S + nxt, S + nxt + 8192)                          \
    }                                                                                  \
    short8v af[4], bfr[4];                                                             \
    _Pragma("unroll") for (int mi = 0; mi < 4; ++mi)                                   \
      af[mi] = *reinterpret_cast<const short8v*>(                                      \
          S + cur + (size_t)(lq * 256 + wm + mi * 16 + l15) * 8);                      \
    _Pragma("unroll") for (int ni = 0; ni < 4; ++ni)                                   \
      bfr[ni] = *reinterpret_cast<const short8v*>(                                     \
          S + cur + 8192 + (size_t)(lq * 128 + wn + ni * 16 + l15) * 8);               \
    _Pragma("unroll") for (int mi = 0; mi < 4; ++mi)                                   \
      _Pragma("unroll") for (int ni = 0; ni < 4; ++ni)                                 \
        acc[mi][ni] = __builtin_amdgcn_mfma_f32_16x16x32_bf16(af[mi], bfr[ni],         \
                                                              acc[mi][ni], 0, 0, 0);   \
  }

// ---------- QKV GEMM: 1152 blocks, mtile-outer per XCD (A-panel L2-hot) ----------
__global__ __launch_bounds__(512, 6)
void gemm_qkv(const unsigned short* __restrict__ A,
              const unsigned short* __restrict__ B,
              unsigned short* __restrict__ KQV) {
  const int ord   = blockIdx.x;             // 0..1151
  const int xcd   = ord & 7;
  const int g     = ord >> 3;               // 0..143
  const int m2    = xcd * 16 + g / 9;       // 0..127 (256-row tile == batch elem)
  const int ntile = g % 9;                  // 0..8; 0-2=K, 3-5=Q, 6-8=V
  const unsigned short* Ab2 = A + (size_t)(m2 * 2) * (KGTOT * 128 * 8);
  const unsigned short* Bb  = B + (size_t)ntile * (KGTOT * 128 * 8);
  GEMM_CORE256(Ab2, Bb)
  // C/D layout: col = lane&15, row = (lane>>4)*4 + reg
  const int half = wave >> 2;               // which hh-half this wave produces
  if (ntile >= 6) {
    unsigned short* Vb = KQV + (size_t)(2 * NBH) * BHSZ;
    const int hh0 = (ntile - 6) * 2;
    __syncthreads();                        // K-loop done; S reusable
#pragma unroll
    for (int p = 0; p < 2; ++p) {
      if (half == p) {
#pragma unroll
        for (int ni = 0; ni < 4; ++ni) {
          const int d = ni * 16 + l15;      // 0..63 within this head
#pragma unroll
          for (int mi = 0; mi < 4; ++mi) {
            const int ttl = wm + mi * 16 + lq * 4;   // 0..255
            const int tg  = ttl >> 3;
            const int tl0 = ttl & 7;                 // 0 or 4
            ushort4 u;
            u.x = f2bf(acc[mi][ni][0]); u.y = f2bf(acc[mi][ni][1]);
            u.z = f2bf(acc[mi][ni][2]); u.w = f2bf(acc[mi][ni][3]);
            *reinterpret_cast<ushort4*>(S + (size_t)((tg * 64 + d) * 8 + tl0)) = u;
          }
        }
      }
      __syncthreads();
      const size_t base = (size_t)(m2 * NHEAD + hh0 + p) * BHSZ;
#pragma unroll
      for (int it = 0; it < 4; ++it) {
        const int f = it * 512 + tid;       // chunk 0..2047 = [tg 32][d 64]
        *reinterpret_cast<short8v*>(Vb + base + (size_t)f * 8) =
            *reinterpret_cast<const short8v*>(S + (size_t)f * 8);
      }
      __syncthreads();
    }
  } else {
    const int type = (ntile >= 3) ? 1 : 0;          // 0=K, 1=Q
    const float sc = type ? 0.051031036307982884f : 1.0f;
    unsigned short* outb = KQV + (size_t)type * NBH * BHSZ;
    const int hp = ntile - type * 3;                // head-pair 0..2
    __syncthreads();                                // K-loop done; S reusable
#pragma unroll
    for (int p = 0; p < 2; ++p) {
      if (half == p) {
#pragma unroll
        for (int ni = 0; ni < 4; ++ni) {
          const int d  = ni * 16 + l15;             // 0..63
          const int c8 = d >> 3;
          const int dl = d & 7;
#pragma unroll
          for (int mi = 0; mi < 4; ++mi) {
            const int lr0 = wm + mi * 16 + lq * 4;  // 0..255
#pragma unroll
            for (int r = 0; r < 4; ++r) {
              const int c  = c8 * 256 + lr0 + r;
              const int cs = c ^ (((c >> 8) ^ (c >> 3)) & 7);
              S[(size_t)cs * 8 + dl] = f2bf(acc[mi][ni][r] * sc);
            }
          }
        }
      }
      __syncthreads();
      const size_t base = (size_t)(m2 * NHEAD + hp * 2 + p) * BHSZ;
#pragma unroll
      for (int it = 0; it < 4; ++it) {
        const int cc = it * 512 + tid;              // chunk 0..2047 = [c8 8][lr 256]
        const int cs = cc ^ (((cc >> 8) ^ (cc >> 3)) & 7);
        const int c8 = cc >> 8;
        const int lr = cc & 255;
        *reinterpret_cast<short8v*>(outb + base + c8 * 2048 + (size_t)lr * 8) =
            *reinterpret_cast<const short8v*>(S + (size_t)cs * 8);
      }
      __syncthreads();
    }
  }
}

// ---------- proj GEMM 256x128: fp32 output, row-major; 4-pass LDS bounce ----------
__global__ __launch_bounds__(512, 6)
void gemm_proj(const unsigned short* __restrict__ A,
               const unsigned short* __restrict__ B,
               float* __restrict__ C, int N) {
  const int ord   = blockIdx.x;             // 0..383
  const int xcd   = ord & 7;
  const int g     = ord >> 3;               // 0..47
  const int m2    = xcd * 16 + g / 3;       // 0..127
  const int ntile = g % 3;                  // 0..2
  const unsigned short* Ab2 = A + (size_t)(m2 * 2) * (KGTOT * 128 * 8);
  const unsigned short* Bb  = B + (size_t)ntile * (KGTOT * 128 * 8);
  GEMM_CORE256(Ab2, Bb)
  float* Sf = reinterpret_cast<float*>(S);  // uses 32KB of the 48
#pragma unroll
  for (int p = 0; p < 4; ++p) {
    __syncthreads();                        // S free (K-loop done / prev pass read)
    if ((wave & 3) == p) {                  // waves with wm == p*64 (both wn halves)
#pragma unroll
      for (int mi = 0; mi < 4; ++mi)
#pragma unroll
        for (int ni = 0; ni < 4; ++ni)
#pragma unroll
          for (int r = 0; r < 4; ++r)
            Sf[(lq * 4 + mi * 16 + r) * 128 + (wn + ni * 16 + l15)] = acc[mi][ni][r];
    }
    __syncthreads();
    const int rowstart = m2 * 256 + p * 64;
#pragma unroll
    for (int it = 0; it < 4; ++it) {
      const int f  = it * 512 + tid;        // float4 idx 0..2047
      const int lr = f >> 5;
      const int lc = (f & 31) * 4;
      *reinterpret_cast<float4*>(&C[(size_t)(rowstart + lr) * N + ntile * 128 + lc]) =
          *reinterpret_cast<const float4*>(&Sf[f * 4]);
    }
  }
}

// ---------- MFMA flash attention, one block per bh (R8 version, unchanged) ----------
__global__ __launch_bounds__(256, 3)
void attn_mfma(const unsigned short* __restrict__ KQV,
               unsigned short* __restrict__ Obf) {
  const int bh   = blockIdx.x;
  const int b    = bh / NHEAD;
  const int h    = bh - b * NHEAD;
  const int tid  = threadIdx.x;
  const int wave = tid >> 6;
  const int lane = tid & 63;
  const int l15  = lane & 15;
  const int lq   = lane >> 4;

  __shared__ __attribute__((aligned(16))) unsigned short Kls[16384];   // [dg 8][t 256][8]
  __shared__ __attribute__((aligned(16))) unsigned short Pt[4][1024];  // per-wave [kg 8][q 16][8]

  const unsigned short* Kb = KQV + (size_t)bh * BHSZ;
  const unsigned short* Qb = KQV + (size_t)(NBH + bh) * BHSZ;
  const unsigned short* Vb = KQV + (size_t)(2 * NBH + bh) * BHSZ;

#pragma unroll
  for (int r = 0; r < 8; ++r) {
    const int i = r * 256 + tid;
    __builtin_amdgcn_global_load_lds(
        (const __attribute__((address_space(1))) unsigned int*)(Kb + (size_t)i * 8),
        (__attribute__((address_space(3))) unsigned int*)(Kls + i * 8), 16, 0, 0);
  }
  __syncthreads();   // only barrier in the kernel

  unsigned short* Pw = Pt[wave];

  for (int j = 0; j < 4; ++j) {
    short8v qa[2];
#pragma unroll
    for (int s = 0; s < 2; ++s)
      qa[s] = *reinterpret_cast<const short8v*>(
          Qb + (size_t)(s * 4 + lq) * 2048 + (size_t)(j * 64 + wave * 16 + l15) * 8);

    float4v o[4];
#pragma unroll
    for (int nf = 0; nf < 4; ++nf) o[nf] = (float4v){0.f, 0.f, 0.f, 0.f};
    float4v lp = (float4v){0.f, 0.f, 0.f, 0.f};

    for (int kt = 0; kt <= j; ++kt) {
      short8v vf[2][4];
#pragma unroll
      for (int s = 0; s < 2; ++s)
#pragma unroll
        for (int nf = 0; nf < 4; ++nf)
          vf[s][nf] = *reinterpret_cast<const short8v*>(
              Vb + (size_t)(kt * 8 + s * 4 + lq) * 512 + (size_t)(nf * 16 + l15) * 8);

      float4v sf[4];
#pragma unroll
      for (int nf = 0; nf < 4; ++nf) sf[nf] = (float4v){0.f, 0.f, 0.f, 0.f};
#pragma unroll
      for (int s = 0; s < 2; ++s) {
        short8v kf[4];
#pragma unroll
        for (int nf = 0; nf < 4; ++nf)
          kf[nf] = *reinterpret_cast<const short8v*>(
              Kls + (size_t)(s * 4 + lq) * 2048 + (size_t)(kt * 64 + nf * 16 + l15) * 8);
#pragma unroll
        for (int nf = 0; nf < 4; ++nf)
          sf[nf] = __builtin_amdgcn_mfma_f32_16x16x32_bf16(qa[s], kf[nf], sf[nf], 0, 0, 0);
      }

      if (kt == j) {
        const int qit = wave * 16 + lq * 4;
#pragma unroll
        for (int nf = 0; nf < 4; ++nf) {
          const int key = nf * 16 + l15;
#pragma unroll
          for (int r = 0; r < 4; ++r)
            if (key > qit + r) sf[nf][r] = -INFINITY;
        }
      }

#pragma unroll
      for (int nf = 0; nf < 4; ++nf) {
        const int kg  = nf * 2 + (l15 >> 3);
        const int pos = l15 & 7;
#pragma unroll
        for (int r = 0; r < 4; ++r) {
          const float p = __expf(sf[nf][r]);
          lp[r] += p;
          Pw[(kg * 16 + lq * 4 + r) * 8 + pos] = f2bf(p);
        }
      }

#pragma unroll
      for (int s = 0; s < 2; ++s) {
        short8v pa = *reinterpret_cast<const short8v*>(
            Pw + (size_t)((s * 4 + lq) * 16 + l15) * 8);
#pragma unroll
        for (int nf = 0; nf < 4; ++nf)
          o[nf] = __builtin_amdgcn_mfma_f32_16x16x32_bf16(pa, vf[s][nf], o[nf], 0, 0, 0);
      }
    }

#pragma unroll
    for (int off = 1; off <= 8; off <<= 1)
#pragma unroll
      for (int r = 0; r < 4; ++r)
        lp[r] += __shfl_xor(lp[r], off);
    float4v inv;
#pragma unroll
    for (int r = 0; r < 4; ++r) inv[r] = 1.f / lp[r];

    // pack normalized O into Pw: [ggl 8][mll 16][pos 8], chunk ^ ggl swizzle
#pragma unroll
    for (int nf = 0; nf < 4; ++nf) {
      const int d   = nf * 16 + l15;
      const int ggl = d >> 3;
      const int pos = d & 7;
#pragma unroll
      for (int r = 0; r < 4; ++r) {
        const int chunk = (ggl * 16 + lq * 4 + r) ^ ggl;
        Pw[chunk * 8 + pos] = f2bf(o[nf][r] * inv[r]);
      }
    }
    const int mb  = b * 2 + (j >> 1);
    const int ml0 = (j & 1) * 64 + wave * 16;
#pragma unroll
    for (int t = 0; t < 2; ++t) {
      const int cc  = t * 64 + lane;
      const int ggl = cc >> 4;
      const int mll = cc & 15;
      *reinterpret_cast<short8v*>(
          Obf + ((size_t)(mb * KGTOT) + h * 8 + ggl) * 1024 + (size_t)(ml0 + mll) * 8) =
          *reinterpret_cast<const short8v*>(Pw + (size_t)(cc ^ ggl) * 8);
    }
  }
}

// ---------- launch ----------

extern "C" void kernel_launch(void* const* d_in, const int* in_sizes, int n_in,
                              void* d_out, int out_size, void* d_ws, size_t ws_size,
                              hipStream_t stream) {
  const float* X     = (const float*)d_in[0];   // (128,256,384)
  const float* Wqkv  = (const float*)d_in[1];   // (384,1152)
  const float* Wproj = (const float*)d_in[2];   // (384,384)
  float* out = (float*)d_out;

  // ws layout (bytes):
  //   KQV bf16: K[768][8][256][8] | Q same | V [768][32][64][8] : 75,497,472
  //   Abf (X bf16 tiled) -> reused as Obf                       : 25,165,824
  //   WqkvT bf16 tiled                                          :    884,736
  //   WprojT bf16 tiled                                         :    294,912
  unsigned short* KQV    = (unsigned short*)d_ws;
  unsigned short* Abf    = (unsigned short*)((char*)d_ws + 75497472);
  unsigned short* WqkvT  = (unsigned short*)((char*)d_ws + 75497472 + 25165824);
  unsigned short* WprojT = (unsigned short*)((char*)d_ws + 75497472 + 25165824 + 884736);
  unsigned short* Obf    = Abf;   // alias: Abf fully consumed before attn writes

  convert_all<<<dim3(XBLOCKS + WBLOCKS), dim3(256), 0, stream>>>(
      X, Wqkv, Wproj, Abf, WqkvT, WprojT);
  gemm_qkv<<<dim3(1152), dim3(512), 0, stream>>>(Abf, WqkvT, KQV);
  attn_mfma<<<dim3(NBH), dim3(256), 0, stream>>>(KQV, Obf);
  gemm_proj<<<dim3(384), dim3(512), 0, stream>>>(Obf, WprojT, out, NEMBD);
}

// Round 11
// 165.276 us; speedup vs baseline: 2.3706x; 2.3706x over previous
//
#include <hip/hip_runtime.h>
#include <hip/hip_bf16.h>

#define BATCH 128
#define TSEQ  256
#define NEMBD 384
#define NHEAD 6
#define HDIM  64
#define C3    1152
#define MROWS 32768      // BATCH*TSEQ
#define KGTOT 48         // NEMBD/8
#define NBH   768        // BATCH*NHEAD
#define BHSZ  16384      // TSEQ*HDIM (ushorts per bh per tensor)

#define NA_CH  (MROWS * KGTOT)   // 1572864 chunks (X)
#define NW1_CH (C3 * KGTOT)      // 55296 (Wqkv)
#define NW2_CH (NEMBD * KGTOT)   // 18432 (Wproj)

#define XBLOCKS 2048             // MROWS/16 row-blocks for X convert
#define WBLOCKS 288              // (NW1_CH+NW2_CH)/256 weight-convert blocks

typedef __attribute__((ext_vector_type(8))) short short8v;
typedef __attribute__((ext_vector_type(4))) float float4v;

// ---------- helpers ----------

__device__ __forceinline__ unsigned short f2bf(float f) {
  __hip_bfloat16 h = __float2bfloat16(f);   // RNE
  unsigned short u;
  __builtin_memcpy(&u, &h, 2);
  return u;
}

// ---------- fused converts ----------
__device__ __forceinline__ void convB_body(const float* __restrict__ W,
                                           unsigned short* __restrict__ out,
                                           int N, int idx) {
  const int nl  = idx & 127;
  const int kgg = (idx >> 7) % KGTOT;
  const int nb  = idx / (128 * KGTOT);
  const int n = nb * 128 + nl;
  short8v v;
#pragma unroll
  for (int j = 0; j < 8; ++j)
    v[j] = (short)f2bf(W[(size_t)(kgg * 8 + j) * N + n]);
  *reinterpret_cast<short8v*>(out + (size_t)idx * 8) = v;
}

__global__ __launch_bounds__(256)
void convert_all(const float* __restrict__ X, const float* __restrict__ W1,
                 const float* __restrict__ W2, unsigned short* __restrict__ Abf,
                 unsigned short* __restrict__ W1T, unsigned short* __restrict__ W2T) {
  const int tid = threadIdx.x;
  if (blockIdx.x < XBLOCKS) {
    __shared__ __attribute__((aligned(16))) unsigned short T[16][392];  // pad 384->392
    const int rb = blockIdx.x;
    const float* Xb = X + (size_t)rb * 16 * NEMBD;
#pragma unroll
    for (int i = 0; i < 6; ++i) {
      const int f4 = i * 256 + tid;          // float4 index 0..1535
      const float4 v = reinterpret_cast<const float4*>(Xb)[f4];
      const int r = f4 / 96;                 // 96 float4 per row
      const int c = (f4 % 96) * 4;
      ushort4 u;
      u.x = f2bf(v.x); u.y = f2bf(v.y); u.z = f2bf(v.z); u.w = f2bf(v.w);
      *reinterpret_cast<ushort4*>(&T[r][c]) = u;
    }
    __syncthreads();
#pragma unroll
    for (int i = 0; i < 3; ++i) {
      const int c2   = i * 256 + tid;        // chunk 0..767 = [kgg 48][ml16 16]
      const int kgg  = c2 >> 4;
      const int ml16 = c2 & 15;
      const short8v v = *reinterpret_cast<const short8v*>(&T[ml16][kgg * 8]);
      const int m  = rb * 16 + ml16;
      const int mb = m >> 7;
      const int ml = m & 127;
      *reinterpret_cast<short8v*>(Abf + ((size_t)(mb * KGTOT + kgg) * 128 + ml) * 8) = v;
    }
  } else {
    const int wi = (blockIdx.x - XBLOCKS) * 256 + tid;
    if (wi < NW1_CH) convB_body(W1, W1T, C3, wi);
    else             convB_body(W2, W2T, NEMBD, wi - NW1_CH);
  }
}

// ---------- GEMM core: BK=32, ping-pong double-buffered gload_lds staging ----------
// R8 structure (verified best). 256 thr / 4 waves, 128x128 tile, 32 KB LDS.
// 256-tile variants refuted: R9 (occupancy loss), R10 (forced bounds -> spill).

#define GEMM_STAGE(Ab, Bb, kb, ASL, BSL)                                               \
  _Pragma("unroll") for (int r = 0; r < 2; ++r) {                                      \
    const int i = r * 256 + tid;                                                       \
    const size_t goff = ((size_t)((kb) * 4 + (i >> 7)) * 128 + (i & 127)) * 8;         \
    __builtin_amdgcn_global_load_lds(                                                  \
        (const __attribute__((address_space(1))) unsigned int*)((Ab) + goff),          \
        (__attribute__((address_space(3))) unsigned int*)((ASL) + i * 8), 16, 0, 0);   \
    __builtin_amdgcn_global_load_lds(                                                  \
        (const __attribute__((address_space(1))) unsigned int*)((Bb) + goff),          \
        (__attribute__((address_space(3))) unsigned int*)((BSL) + i * 8), 16, 0, 0);   \
  }

#define GEMM_CORE(Ab, Bb)                                                              \
  __shared__ __attribute__((aligned(16))) unsigned short S[16384];                     \
  const int tid  = threadIdx.x;                                                        \
  const int wave = tid >> 6;                                                           \
  const int lane = tid & 63;                                                           \
  const int wm  = (wave & 1) * 64;                                                     \
  const int wn  = (wave >> 1) * 64;                                                    \
  const int l15 = lane & 15;                                                           \
  const int lq  = lane >> 4;                                                           \
  float4v acc[4][4];                                                                   \
  _Pragma("unroll") for (int i = 0; i < 4; ++i)                                        \
    _Pragma("unroll") for (int j = 0; j < 4; ++j)                                      \
      acc[i][j] = (float4v){0.f, 0.f, 0.f, 0.f};                                       \
  GEMM_STAGE(Ab, Bb, 0, S, S + 4096)                                                   \
  for (int kb = 0; kb < KGTOT / 4; ++kb) {                                             \
    const int cur = (kb & 1) * 8192;                                                   \
    const int nxt = 8192 - cur;                                                        \
    __syncthreads();                                                                   \
    if (kb + 1 < KGTOT / 4) {                                                          \
      GEMM_STAGE(Ab, Bb, kb + 1, S + nxt, S + nxt + 4096)                              \
    }                                                                                  \
    short8v af[4], bfr[4];                                                             \
    _Pragma("unroll") for (int mi = 0; mi < 4; ++mi)                                   \
      af[mi] = *reinterpret_cast<const short8v*>(                                      \
          S + cur + (size_t)(lq * 128 + wm + mi * 16 + l15) * 8);                      \
    _Pragma("unroll") for (int ni = 0; ni < 4; ++ni)                                   \
      bfr[ni] = *reinterpret_cast<const short8v*>(                                     \
          S + cur + 4096 + (size_t)(lq * 128 + wn + ni * 16 + l15) * 8);               \
    _Pragma("unroll") for (int mi = 0; mi < 4; ++mi)                                   \
      _Pragma("unroll") for (int ni = 0; ni < 4; ++ni)                                 \
        acc[mi][ni] = __builtin_amdgcn_mfma_f32_16x16x32_bf16(af[mi], bfr[ni],         \
                                                              acc[mi][ni], 0, 0, 0);   \
  }

// ---------- QKV GEMM ----------
// Grid 2304, mtile-outer per XCD (R9's proven L2 ordering: the 9 ntile blocks
// sharing one 96KB A-panel run consecutively on one XCD -> A L2-hot, stage
// loads hit L2 (~200cy) instead of HBM (~900cy) at the barrier drain).
// Epilogues (R8 verified): K/Q LDS-bounce with chunk-XOR swizzle; V LDS-bounce
// [hh 2][tg 16][d 64][tl 8] -> 8 coalesced 16B stores/thread.
__global__ __launch_bounds__(256)
void gemm_qkv(const unsigned short* __restrict__ A,
              const unsigned short* __restrict__ B,
              unsigned short* __restrict__ KQV) {
  const int ord   = blockIdx.x;
  const int xcd   = ord & 7;
  const int g     = ord >> 3;               // 0..287
  const int mtile = xcd * 32 + g / 9;       // consecutive g share the A-panel
  const int ntile = g % 9;                  // 0..8; 0-2=K, 3-5=Q, 6-8=V
  const unsigned short* Ab = A + (size_t)mtile * (KGTOT * 128 * 8);
  const unsigned short* Bb = B + (size_t)ntile * (KGTOT * 128 * 8);
  GEMM_CORE(Ab, Bb)
  // C/D layout: col = lane&15, row = (lane>>4)*4 + reg
  if (ntile >= 6) {
    unsigned short* Vb = KQV + (size_t)(2 * NBH) * BHSZ;
    const int hh0 = (ntile - 6) * 2;
    const int bb  = mtile >> 1;
    const int tg0 = (mtile & 1) * 16;
    __syncthreads();                                // K-loop done; S reusable
#pragma unroll
    for (int ni = 0; ni < 4; ++ni) {
      const int lc = wn + ni * 16 + l15;            // local col 0..127
      const int hh = lc >> 6;
      const int d  = lc & 63;
#pragma unroll
      for (int mi = 0; mi < 4; ++mi) {
        const int ttl = wm + mi * 16 + lq * 4;      // local row base (%4==0)
        const int tg  = ttl >> 3;
        const int tl0 = ttl & 7;                    // 0 or 4
        ushort4 u;
        u.x = f2bf(acc[mi][ni][0]); u.y = f2bf(acc[mi][ni][1]);
        u.z = f2bf(acc[mi][ni][2]); u.w = f2bf(acc[mi][ni][3]);
        *reinterpret_cast<ushort4*>(
            S + (size_t)(((hh * 16 + tg) * 64 + d) * 8 + tl0)) = u;
      }
    }
    __syncthreads();
#pragma unroll
    for (int it = 0; it < 8; ++it) {
      const int f  = it * 2048 + tid * 8;
      const int cc = f >> 3;
      const int d  = cc & 63;
      const int tg = (cc >> 6) & 15;
      const int hh = cc >> 10;
      *reinterpret_cast<short8v*>(
          Vb + (size_t)(bb * NHEAD + hh0 + hh) * BHSZ + (tg0 + tg) * 512 + d * 8) =
          *reinterpret_cast<const short8v*>(S + f);
    }
  } else {
    const int type = (ntile >= 3) ? 1 : 0;          // 0=K, 1=Q
    const float sc = type ? 0.051031036307982884f : 1.0f;
    unsigned short* outb = KQV + (size_t)type * NBH * BHSZ;
    const int hp = ntile - type * 3;                // head-pair 0..2
    const int bb = mtile >> 1;                      // batch index
    const int t0 = (mtile & 1) * 128;               // t-offset of this mtile
    __syncthreads();                                // K-loop done; S reusable
#pragma unroll
    for (int ni = 0; ni < 4; ++ni) {
      const int lc = wn + ni * 16 + l15;            // local col 0..127
      const int c8 = lc >> 3;
      const int dl = lc & 7;
#pragma unroll
      for (int mi = 0; mi < 4; ++mi) {
        const int lr0 = wm + lq * 4 + mi * 16;
#pragma unroll
        for (int r = 0; r < 4; ++r) {
          const int c  = c8 * 128 + lr0 + r;
          const int cs = c ^ (((c >> 7) ^ (c >> 3)) & 7);
          S[(size_t)cs * 8 + dl] = f2bf(acc[mi][ni][r] * sc);
        }
      }
    }
    __syncthreads();
#pragma unroll
    for (int it = 0; it < 8; ++it) {
      const int f   = it * 2048 + tid * 8;
      const int cc  = f >> 3;
      const int cs  = cc ^ (((cc >> 7) ^ (cc >> 3)) & 7);
      const int c8  = cc >> 7;
      const int lr  = cc & 127;
      const int hh  = hp * 2 + (c8 >> 3);
      const int dg  = c8 & 7;
      *reinterpret_cast<short8v*>(
          outb + (size_t)(bb * NHEAD + hh) * BHSZ + dg * 2048 + (size_t)(t0 + lr) * 8) =
          *reinterpret_cast<const short8v*>(S + (size_t)cs * 8);
    }
  }
}

// ---------- proj GEMM: fp32 output, row-major; LDS-bounce epilogue ----------
__global__ __launch_bounds__(256)
void gemm_proj(const unsigned short* __restrict__ A,
               const unsigned short* __restrict__ B,
               float* __restrict__ C, int N) {
  const int ord   = blockIdx.x;
  const int xcd   = ord & 7;
  const int g     = ord >> 3;               // 0..95
  const int mtile = xcd * 32 + g / 3;       // mtile-outer (A-panel L2-hot)
  const int ntile = g % 3;                  // 0..2
  const unsigned short* Ab = A + (size_t)mtile * (KGTOT * 128 * 8);
  const unsigned short* Bb = B + (size_t)ntile * (KGTOT * 128 * 8);
  GEMM_CORE(Ab, Bb)
  float* Sf = reinterpret_cast<float*>(S);  // 8192 floats
#pragma unroll
  for (int pass = 0; pass < 2; ++pass) {
    __syncthreads();                        // S free (K-loop done / pass0 read)
    if ((wave & 1) == pass) {               // waves with wm == pass*64
#pragma unroll
      for (int mi = 0; mi < 4; ++mi)
#pragma unroll
        for (int ni = 0; ni < 4; ++ni)
#pragma unroll
          for (int r = 0; r < 4; ++r)
            Sf[(lq * 4 + mi * 16 + r) * 128 + (wn + ni * 16 + l15)] = acc[mi][ni][r];
    }
    __syncthreads();
    const int rowstart = mtile * 128 + pass * 64;
#pragma unroll
    for (int it = 0; it < 8; ++it) {
      const int f  = it * 1024 + tid * 4;
      const int lr = f >> 7;
      const int lc = f & 127;
      *reinterpret_cast<float4*>(&C[(size_t)(rowstart + lr) * N + ntile * 128 + lc]) =
          *reinterpret_cast<const float4*>(&Sf[f]);
    }
  }
}

// ---------- MFMA flash attention, one block per bh (R8 version, unchanged) ----------
__global__ __launch_bounds__(256, 3)
void attn_mfma(const unsigned short* __restrict__ KQV,
               unsigned short* __restrict__ Obf) {
  const int bh   = blockIdx.x;
  const int b    = bh / NHEAD;
  const int h    = bh - b * NHEAD;
  const int tid  = threadIdx.x;
  const int wave = tid >> 6;
  const int lane = tid & 63;
  const int l15  = lane & 15;
  const int lq   = lane >> 4;

  __shared__ __attribute__((aligned(16))) unsigned short Kls[16384];   // [dg 8][t 256][8]
  __shared__ __attribute__((aligned(16))) unsigned short Pt[4][1024];  // per-wave [kg 8][q 16][8]

  const unsigned short* Kb = KQV + (size_t)bh * BHSZ;
  const unsigned short* Qb = KQV + (size_t)(NBH + bh) * BHSZ;
  const unsigned short* Vb = KQV + (size_t)(2 * NBH + bh) * BHSZ;

#pragma unroll
  for (int r = 0; r < 8; ++r) {
    const int i = r * 256 + tid;
    __builtin_amdgcn_global_load_lds(
        (const __attribute__((address_space(1))) unsigned int*)(Kb + (size_t)i * 8),
        (__attribute__((address_space(3))) unsigned int*)(Kls + i * 8), 16, 0, 0);
  }
  __syncthreads();   // only barrier in the kernel

  unsigned short* Pw = Pt[wave];

  for (int j = 0; j < 4; ++j) {
    short8v qa[2];
#pragma unroll
    for (int s = 0; s < 2; ++s)
      qa[s] = *reinterpret_cast<const short8v*>(
          Qb + (size_t)(s * 4 + lq) * 2048 + (size_t)(j * 64 + wave * 16 + l15) * 8);

    float4v o[4];
#pragma unroll
    for (int nf = 0; nf < 4; ++nf) o[nf] = (float4v){0.f, 0.f, 0.f, 0.f};
    float4v lp = (float4v){0.f, 0.f, 0.f, 0.f};

    for (int kt = 0; kt <= j; ++kt) {
      short8v vf[2][4];
#pragma unroll
      for (int s = 0; s < 2; ++s)
#pragma unroll
        for (int nf = 0; nf < 4; ++nf)
          vf[s][nf] = *reinterpret_cast<const short8v*>(
              Vb + (size_t)(kt * 8 + s * 4 + lq) * 512 + (size_t)(nf * 16 + l15) * 8);

      float4v sf[4];
#pragma unroll
      for (int nf = 0; nf < 4; ++nf) sf[nf] = (float4v){0.f, 0.f, 0.f, 0.f};
#pragma unroll
      for (int s = 0; s < 2; ++s) {
        short8v kf[4];
#pragma unroll
        for (int nf = 0; nf < 4; ++nf)
          kf[nf] = *reinterpret_cast<const short8v*>(
              Kls + (size_t)(s * 4 + lq) * 2048 + (size_t)(kt * 64 + nf * 16 + l15) * 8);
#pragma unroll
        for (int nf = 0; nf < 4; ++nf)
          sf[nf] = __builtin_amdgcn_mfma_f32_16x16x32_bf16(qa[s], kf[nf], sf[nf], 0, 0, 0);
      }

      if (kt == j) {
        const int qit = wave * 16 + lq * 4;
#pragma unroll
        for (int nf = 0; nf < 4; ++nf) {
          const int key = nf * 16 + l15;
#pragma unroll
          for (int r = 0; r < 4; ++r)
            if (key > qit + r) sf[nf][r] = -INFINITY;
        }
      }

#pragma unroll
      for (int nf = 0; nf < 4; ++nf) {
        const int kg  = nf * 2 + (l15 >> 3);
        const int pos = l15 & 7;
#pragma unroll
        for (int r = 0; r < 4; ++r) {
          const float p = __expf(sf[nf][r]);
          lp[r] += p;
          Pw[(kg * 16 + lq * 4 + r) * 8 + pos] = f2bf(p);
        }
      }

#pragma unroll
      for (int s = 0; s < 2; ++s) {
        short8v pa = *reinterpret_cast<const short8v*>(
            Pw + (size_t)((s * 4 + lq) * 16 + l15) * 8);
#pragma unroll
        for (int nf = 0; nf < 4; ++nf)
          o[nf] = __builtin_amdgcn_mfma_f32_16x16x32_bf16(pa, vf[s][nf], o[nf], 0, 0, 0);
      }
    }

#pragma unroll
    for (int off = 1; off <= 8; off <<= 1)
#pragma unroll
      for (int r = 0; r < 4; ++r)
        lp[r] += __shfl_xor(lp[r], off);
    float4v inv;
#pragma unroll
    for (int r = 0; r < 4; ++r) inv[r] = 1.f / lp[r];

    // pack normalized O into Pw: [ggl 8][mll 16][pos 8], chunk ^ ggl swizzle
#pragma unroll
    for (int nf = 0; nf < 4; ++nf) {
      const int d   = nf * 16 + l15;
      const int ggl = d >> 3;
      const int pos = d & 7;
#pragma unroll
      for (int r = 0; r < 4; ++r) {
        const int chunk = (ggl * 16 + lq * 4 + r) ^ ggl;
        Pw[chunk * 8 + pos] = f2bf(o[nf][r] * inv[r]);
      }
    }
    const int mb  = b * 2 + (j >> 1);
    const int ml0 = (j & 1) * 64 + wave * 16;
#pragma unroll
    for (int t = 0; t < 2; ++t) {
      const int cc  = t * 64 + lane;
      const int ggl = cc >> 4;
      const int mll = cc & 15;
      *reinterpret_cast<short8v*>(
          Obf + ((size_t)(mb * KGTOT) + h * 8 + ggl) * 1024 + (size_t)(ml0 + mll) * 8) =
          *reinterpret_cast<const short8v*>(Pw + (size_t)(cc ^ ggl) * 8);
    }
  }
}

// ---------- launch ----------

extern "C" void kernel_launch(void* const* d_in, const int* in_sizes, int n_in,
                              void* d_out, int out_size, void* d_ws, size_t ws_size,
                              hipStream_t stream) {
  const float* X     = (const float*)d_in[0];   // (128,256,384)
  const float* Wqkv  = (const float*)d_in[1];   // (384,1152)
  const float* Wproj = (const float*)d_in[2];   // (384,384)
  float* out = (float*)d_out;

  // ws layout (bytes):
  //   KQV bf16: K[768][8][256][8] | Q same | V [768][32][64][8] : 75,497,472
  //   Abf (X bf16 tiled) -> reused as Obf                       : 25,165,824
  //   WqkvT bf16 tiled                                          :    884,736
  //   WprojT bf16 tiled                                         :    294,912
  unsigned short* KQV    = (unsigned short*)d_ws;
  unsigned short* Abf    = (unsigned short*)((char*)d_ws + 75497472);
  unsigned short* WqkvT  = (unsigned short*)((char*)d_ws + 75497472 + 25165824);
  unsigned short* WprojT = (unsigned short*)((char*)d_ws + 75497472 + 25165824 + 884736);
  unsigned short* Obf    = Abf;   // alias: Abf fully consumed before attn writes

  dim3 blk(256);
  convert_all<<<dim3(XBLOCKS + WBLOCKS), blk, 0, stream>>>(
      X, Wqkv, Wproj, Abf, WqkvT, WprojT);
  gemm_qkv<<<dim3(2304), blk, 0, stream>>>(Abf, WqkvT, KQV);
  attn_mfma<<<dim3(NBH), blk, 0, stream>>>(KQV, Obf);
  gemm_proj<<<dim3(768), blk, 0, stream>>>(Obf, WprojT, out, NEMBD);
}